// Round 12
// baseline (250.589 us; speedup 1.0000x reference)
//
#include <hip/hip_runtime.h>

typedef unsigned short u16;
typedef __bf16 bf16x8 __attribute__((ext_vector_type(8)));
typedef float floatx4 __attribute__((ext_vector_type(4)));
typedef unsigned as1_u32 __attribute__((address_space(1)));
typedef unsigned as3_u32 __attribute__((address_space(3)));

// ---- helpers ----
__device__ inline u16 f2bf(float f) {
    unsigned int u = __builtin_bit_cast(unsigned int, f);
    u += 0x7fffu + ((u >> 16) & 1u);   // RNE
    return (u16)(u >> 16);
}
__device__ inline floatx4 mfma16(bf16x8 a, bf16x8 b, floatx4 c) {
    return __builtin_amdgcn_mfma_f32_16x16x32_bf16(a, b, c, 0, 0, 0);
}
// async global->LDS, 16 B per lane; lds base must be wave-uniform (HW adds lane*16)
__device__ inline void gld16(const u16* g, u16* l) {
    __builtin_amdgcn_global_load_lds((const as1_u32*)g, (as3_u32*)l, 16, 0, 0);
}
// hi16(a) | hi16(b)<<16 via v_perm_b32  (bf16 truncation pack)
__device__ inline unsigned permpack(float lo, float hi) {
    return __builtin_amdgcn_perm(__builtin_bit_cast(unsigned, hi),
                                 __builtin_bit_cast(unsigned, lo), 0x07060302u);
}

#define NSEQ 2048
#define DIM  1024
#define HEADS 16
#define DHEAD 64
// Q pre-scale folds softmax scale AND log2(e): 0.125 * 1.44269504
#define QSCALE 0.18033688f
// fixed softmax shift (log2 domain)
#define CSHIFT 4.328085f

// =====================================================================
// Fused pre-pass: block-range dispatch.
// =====================================================================
__device__ inline void transpose_tile(const float* __restrict__ src,
                                      u16* __restrict__ dst, int ncols,
                                      int n0, int k0, int t) {
    __shared__ u16 tile[64][72];
    #pragma unroll
    for (int rr = 0; rr < 4; rr++) {
        const int k = (t >> 4) + rr * 16;
        const int n = (t & 15) * 4;
        float4 v = *(const float4*)&src[(size_t)(k0 + k) * ncols + n0 + n];
        tile[n + 0][k] = f2bf(v.x); tile[n + 1][k] = f2bf(v.y);
        tile[n + 2][k] = f2bf(v.z); tile[n + 3][k] = f2bf(v.w);
    }
    __syncthreads();
    #pragma unroll
    for (int ww = 0; ww < 2; ww++) {
        const int idx = t + ww * 256;
        const int n = idx >> 3, g = idx & 7;
        u16 tmp[8] __attribute__((aligned(16)));
        #pragma unroll
        for (int i = 0; i < 8; i++) tmp[i] = tile[n][g * 8 + i];
        *(uint4*)&dst[(size_t)(n0 + n) * 1024 + k0 + g * 8] = *(const uint4*)tmp;
    }
}

__global__ __launch_bounds__(256) void prep_fused(
    const float* __restrict__ x,  u16* __restrict__ xb,
    const float* __restrict__ Wq, const float* __restrict__ Wkv,
    u16* __restrict__ Wt)
{
    const int bid = blockIdx.x;
    const int t = threadIdx.x;
    if (bid < 4096) {
        const size_t i = ((size_t)bid * 256 + t) * 8;
        float4 a = *(const float4*)&x[i];
        float4 b = *(const float4*)&x[i + 4];
        u16 o[8] __attribute__((aligned(16)));
        o[0] = f2bf(a.x); o[1] = f2bf(a.y); o[2] = f2bf(a.z); o[3] = f2bf(a.w);
        o[4] = f2bf(b.x); o[5] = f2bf(b.y); o[6] = f2bf(b.z); o[7] = f2bf(b.w);
        *(uint4*)&xb[i] = *(const uint4*)o;
    } else if (bid < 4352) {
        const int v = bid - 4096;
        transpose_tile(Wq, Wt, 1024, (v & 15) * 64, (v >> 4) * 64, t);
    } else {
        const int v = bid - 4352;
        transpose_tile(Wkv, Wt + (size_t)1024 * 1024, 2048, (v & 31) * 64, (v >> 5) * 64, t);
    }
}

__global__ __launch_bounds__(256) void transpose_conv(const float* __restrict__ src,
                                                      u16* __restrict__ dst, int ncols) {
    transpose_tile(src, dst, ncols, blockIdx.x * 64, blockIdx.y * 64, threadIdx.x);
}

// =====================================================================
// Kernel 1 v7: 8-phase-style port (m201 template). 256x128 tile, BK=64,
// 512 thr (8 waves = 4M x 2N), ring-3 LDS (144KB, 1 block/CU), 768 blocks
// = exactly 3 full CU passes. Per K-tile, 4 quadrant-phases:
//   {ds_read subtile | 2 stage issues | s_barrier | lgkmcnt(0)+schedbar |
//    setprio(1) 8xMFMA setprio(0) | s_barrier}
// bf0/bf1 stay in regs so ph3 is pure MFMA. vmcnt(6) ONCE per K-tile at
// ph3 (prefetch distance 2 tiles; never drained mid-loop).
// LDS layout+swizzle per 32-col half identical to verified v6.
// =====================================================================
__global__ __launch_bounds__(512, 2) void qkv_gemm_v7(
    const u16* __restrict__ xb, const u16* __restrict__ Wt,
    u16* __restrict__ q_ws, u16* __restrict__ k_ws, u16* __restrict__ v_ws)
{
    __shared__ u16 As[3][2][256 * 32];   // [buf][ks-half][256 rows x 32 cols]
    __shared__ u16 Bs[3][2][128 * 32];

    const int n0 = blockIdx.x * 128;
    const int m0 = blockIdx.y * 256;
    const int t = threadIdx.x, lane = t & 63, w = t >> 6;
    const int wr = w >> 1, wc = w & 1;           // 4 M-waves x 2 N-waves
    const int quad = lane >> 4, l16 = lane & 15;
    const int rsw  = ((l16 >> 1) & 3);
    const int roff = ((quad ^ rsw) * 8);         // conflict-free read chunk

    // staging: 128-row slice per issue; wave w rows [w*16, w*16+16)
    const int srow = w * 16 + (lane >> 2);       // 0..127
    const int lk   = (((lane & 3) ^ ((lane >> 3) & 3)) * 8);  // pre-swizzled src chunk

    floatx4 acc[4][4];
    #pragma unroll
    for (int i = 0; i < 4; i++)
        #pragma unroll
        for (int j = 0; j < 4; j++) acc[i][j] = floatx4{0.f, 0.f, 0.f, 0.f};

#define STA(buf, a, kt) \
    gld16(&xb[(size_t)(m0 + ((a) >> 1) * 128 + srow) * DIM + (size_t)(kt) * 64 \
              + ((a) & 1) * 32 + lk], \
          &As[buf][(a) & 1][(((a) >> 1) * 128 + w * 16) * 32])
#define STB(buf, bi, kt) \
    gld16(&Wt[(size_t)(n0 + srow) * DIM + (size_t)(kt) * 64 + (bi) * 32 + lk], \
          &Bs[buf][bi][(w * 16) * 32])
#define RA(dst, i, cb) do { \
    dst[0] = *(const bf16x8*)&As[cb][0][(wr * 64 + (i) * 16 + l16) * 32 + roff]; \
    dst[1] = *(const bf16x8*)&As[cb][1][(wr * 64 + (i) * 16 + l16) * 32 + roff]; \
} while (0)
#define RB(dst, j, cb) do { \
    dst[0] = *(const bf16x8*)&Bs[cb][0][(wc * 64 + (j) * 16 + l16) * 32 + roff]; \
    dst[1] = *(const bf16x8*)&Bs[cb][1][(wc * 64 + (j) * 16 + l16) * 32 + roff]; \
} while (0)

    // prologue: tiles 0,1 -> bufs 0,1 (12 issues); wait tile 0 (6 newest stay)
    STA(0, 0, 0); STA(0, 1, 0); STA(0, 2, 0); STA(0, 3, 0); STB(0, 0, 0); STB(0, 1, 0);
    STA(1, 0, 1); STA(1, 1, 1); STA(1, 2, 1); STA(1, 3, 1); STB(1, 0, 1); STB(1, 1, 1);
    asm volatile("s_waitcnt vmcnt(6)" ::: "memory");
    __builtin_amdgcn_s_barrier();

    int cur = 0, stb = 2;
    for (int kt = 0; kt < 16; kt++) {
        bf16x8 af0[2], af1[2], af2[2], af3[2];
        bf16x8 bf0[2], bf1[2], bf2[2], bf3[2];

        // ---- phase 0: Q00 ----
        RA(af0, 0, cur); RA(af1, 1, cur);
        RB(bf0, 0, cur); RB(bf1, 1, cur);
        if (kt < 14) { STA(stb, 0, kt + 2); STA(stb, 1, kt + 2); }
        __builtin_amdgcn_s_barrier();
        asm volatile("s_waitcnt lgkmcnt(0)" ::: "memory");
        __builtin_amdgcn_sched_barrier(0);
        __builtin_amdgcn_s_setprio(1);
        #pragma unroll
        for (int ks = 0; ks < 2; ks++) {
            acc[0][0] = mfma16(af0[ks], bf0[ks], acc[0][0]);
            acc[0][1] = mfma16(af0[ks], bf1[ks], acc[0][1]);
            acc[1][0] = mfma16(af1[ks], bf0[ks], acc[1][0]);
            acc[1][1] = mfma16(af1[ks], bf1[ks], acc[1][1]);
        }
        __builtin_amdgcn_s_setprio(0);
        __builtin_amdgcn_s_barrier();

        // ---- phase 1: Q01 ----
        RB(bf2, 2, cur); RB(bf3, 3, cur);
        if (kt < 14) { STA(stb, 2, kt + 2); STA(stb, 3, kt + 2); }
        __builtin_amdgcn_s_barrier();
        asm volatile("s_waitcnt lgkmcnt(0)" ::: "memory");
        __builtin_amdgcn_sched_barrier(0);
        __builtin_amdgcn_s_setprio(1);
        #pragma unroll
        for (int ks = 0; ks < 2; ks++) {
            acc[0][2] = mfma16(af0[ks], bf2[ks], acc[0][2]);
            acc[0][3] = mfma16(af0[ks], bf3[ks], acc[0][3]);
            acc[1][2] = mfma16(af1[ks], bf2[ks], acc[1][2]);
            acc[1][3] = mfma16(af1[ks], bf3[ks], acc[1][3]);
        }
        __builtin_amdgcn_s_setprio(0);
        __builtin_amdgcn_s_barrier();

        // ---- phase 2: Q11 ----
        RA(af2, 2, cur); RA(af3, 3, cur);
        if (kt < 14) { STB(stb, 0, kt + 2); STB(stb, 1, kt + 2); }
        __builtin_amdgcn_s_barrier();
        asm volatile("s_waitcnt lgkmcnt(0)" ::: "memory");
        __builtin_amdgcn_sched_barrier(0);
        __builtin_amdgcn_s_setprio(1);
        #pragma unroll
        for (int ks = 0; ks < 2; ks++) {
            acc[2][2] = mfma16(af2[ks], bf2[ks], acc[2][2]);
            acc[2][3] = mfma16(af2[ks], bf3[ks], acc[2][3]);
            acc[3][2] = mfma16(af3[ks], bf2[ks], acc[3][2]);
            acc[3][3] = mfma16(af3[ks], bf3[ks], acc[3][3]);
        }
        __builtin_amdgcn_s_setprio(0);
        __builtin_amdgcn_s_barrier();

        // ---- phase 3: Q10 (pure MFMA; bf0/bf1 still live) ----
        __builtin_amdgcn_s_setprio(1);
        #pragma unroll
        for (int ks = 0; ks < 2; ks++) {
            acc[2][0] = mfma16(af2[ks], bf0[ks], acc[2][0]);
            acc[2][1] = mfma16(af2[ks], bf1[ks], acc[2][1]);
            acc[3][0] = mfma16(af3[ks], bf0[ks], acc[3][0]);
            acc[3][1] = mfma16(af3[ks], bf1[ks], acc[3][1]);
        }
        __builtin_amdgcn_s_setprio(0);
        // once-per-tile counted wait: next tile's 6 oldest loads done,
        // freshly staged 6 stay in flight
        if (kt < 14)       asm volatile("s_waitcnt vmcnt(6)" ::: "memory");
        else if (kt == 14) asm volatile("s_waitcnt vmcnt(0)" ::: "memory");
        __builtin_amdgcn_s_barrier();

        cur = (cur == 2) ? 0 : cur + 1;
        stb = (stb == 2) ? 0 : stb + 1;
    }
#undef STA
#undef STB
#undef RA
#undef RB

    const int seg = n0 >> 10;
    #pragma unroll
    for (int nj = 0; nj < 4; nj++) {
        const int n  = n0 + wc * 64 + nj * 16 + l16;
        const int nn = n & 1023;
        const int h  = nn >> 6, d = nn & 63;
        #pragma unroll
        for (int mi = 0; mi < 4; mi++) {
            const int mb = m0 + wr * 64 + mi * 16 + quad * 4;
            const int b = mb >> 11, ib = mb & (NSEQ - 1);
            if (seg == 0) {
                #pragma unroll
                for (int r = 0; r < 4; r++)
                    q_ws[(((size_t)(b * HEADS + h)) * NSEQ + ib + r) * DHEAD + d] =
                        f2bf(acc[mi][nj][r] * QSCALE);
            } else if (seg == 1) {
                #pragma unroll
                for (int r = 0; r < 4; r++)
                    k_ws[(((size_t)(b * HEADS + h)) * NSEQ + ib + r) * DHEAD + d] =
                        f2bf(acc[mi][nj][r]);
            } else {
                u16 tmp[4] __attribute__((aligned(8)));
                #pragma unroll
                for (int r = 0; r < 4; r++) tmp[r] = f2bf(acc[mi][nj][r]);
                *(uint2*)&v_ws[(((size_t)(b * HEADS + h)) * DHEAD + d) * NSEQ + ib] =
                    *(const uint2*)tmp;
            }
        }
    }
}

// =====================================================================
// Kernel 2 v11 (unchanged, passed r11): balanced pairing + ones-MFMA l.
// =====================================================================
__global__ __launch_bounds__(256) void attn_v11(
    const u16* __restrict__ q_ws, const u16* __restrict__ k_ws,
    const u16* __restrict__ v_ws, u16* __restrict__ attn_ws)
{
    __shared__ u16 kds[2][64 * 64];       // [j][chunk-swizzled d]
    __shared__ u16 vds[2][64 * 64];       // [d][chunk-swizzled j]
    __shared__ u16 p_lds[4 * 1024];       // per-wave 2KB, chunk-column-major

    const int bid = blockIdx.x;           // 1024 = 16 pairs x 64 bh
    const int bh  = bid & 63;
    const int pr  = bid >> 6;             // 0..15
    const int b   = bh >> 4, h = bh & 15;

    const u16* qb = q_ws + (size_t)bh * NSEQ * DHEAD;
    const u16* kb = k_ws + (size_t)bh * NSEQ * DHEAD;
    const u16* vb = v_ws + (size_t)bh * DHEAD * NSEQ;

    const int t    = threadIdx.x;
    const int lane = t & 63, w = t >> 6;
    const int quad = lane >> 4, l16 = lane & 15;

    const int srow8 = lane >> 3;
    const int chunk = (lane & 7) ^ srow8;
    const int krow  = w * 16 + srow8;
    const size_t koff = (size_t)krow * DHEAD + chunk * 8;
    const size_t voff = (size_t)krow * NSEQ + chunk * 8;
    u16* klbase = (u16*)&kds[0][0] + w * 1024;
    u16* vlbase = (u16*)&vds[0][0] + w * 1024;
    const int sw = (l16 & 7);

    bf16x8 ones;
    #pragma unroll
    for (int i = 0; i < 8; i++) ones[i] = (__bf16)1.0f;

    for (int seg = 0; seg < 2; seg++) {
        const int tq = seg ? pr : (31 - pr);     // heavy tile first
        const int i0 = tq * 64;
        const int jt_max = tq;

        bf16x8 qf[2];
        #pragma unroll
        for (int dg = 0; dg < 2; dg++)
            qf[dg] = *(const bf16x8*)&qb[(size_t)(i0 + w * 16 + l16) * DHEAD
                                         + dg * 32 + quad * 8];

        floatx4 lacc = floatx4{0.f, 0.f, 0.f, 0.f};
        floatx4 acc[4];
        #pragma unroll
        for (int dg = 0; dg < 4; dg++) acc[dg] = floatx4{0.f, 0.f, 0.f, 0.f};

        __syncthreads();   // protect K/V buffers vs previous segment's reads
        gld16(&kb[koff],             klbase);
        gld16(&kb[koff + 8 * DHEAD], klbase + 512);
        gld16(&vb[voff],             vlbase);
        gld16(&vb[voff + 8 * NSEQ],  vlbase + 512);

        for (int jt = 0; jt <= jt_max; jt++) {
            const int cur = jt & 1;
            __syncthreads();   // drains vmcnt+lgkmcnt: buf[cur] ready

            if (jt < jt_max) {
                const size_t j64 = (size_t)(jt + 1) * 64;
                const int nb = (cur ^ 1) * 4096;
                gld16(&kb[j64 * DHEAD + koff],             klbase + nb);
                gld16(&kb[j64 * DHEAD + koff + 8 * DHEAD], klbase + nb + 512);
                gld16(&vb[j64 + voff],                     vlbase + nb);
                gld16(&vb[j64 + voff + 8 * NSEQ],          vlbase + nb + 512);
            }

            const u16* kl = &kds[cur][0];
            const u16* vl = &vds[cur][0];
            const int j0 = jt * 64;

            floatx4 s[4];
            #pragma unroll
            for (int g = 0; g < 4; g++)
                s[g] = floatx4{-CSHIFT, -CSHIFT, -CSHIFT, -CSHIFT};
            __builtin_amdgcn_s_setprio(1);
            #pragma unroll
            for (int dg = 0; dg < 2; dg++)
                #pragma unroll
                for (int g = 0; g < 4; g++) {
                    bf16x8 kf = *(const bf16x8*)&kl[(g * 16 + l16) * 64
                                                    + (((dg * 4 + quad) ^ sw) * 8)];
                    s[g] = mfma16(kf, qf[dg], s[g]);
                }
            __builtin_amdgcn_s_setprio(0);

            if (j0 + 63 > i0 + w * 16) {
                const int i = i0 + w * 16 + l16;
                #pragma unroll
                for (int g = 0; g < 4; g++) {
                    const int jb = j0 + g * 16 + quad * 4;
                    #pragma unroll
                    for (int r = 0; r < 4; r++)
                        if (jb + r > i) s[g][r] = -1e30f;
                }
            }

            #pragma unroll
            for (int g = 0; g < 4; g++) {
                #pragma unroll
                for (int r = 0; r < 4; r++)
                    s[g][r] = __builtin_amdgcn_exp2f(s[g][r]);
                uint2 pk;
                pk.x = permpack(s[g][0], s[g][1]);
                pk.y = permpack(s[g][2], s[g][3]);
                const int c = 2 * g + (quad >> 1);
                *(uint2*)&p_lds[w * 1024 + (c >> 2) * 512 + (c & 3) * 128
                                + l16 * 8 + (quad & 1) * 4] = pk;
            }
            asm volatile("s_waitcnt lgkmcnt(0)" ::: "memory");

            __builtin_amdgcn_s_setprio(1);
            #pragma unroll
            for (int jg = 0; jg < 2; jg++) {
                bf16x8 pf = *(const bf16x8*)&p_lds[w * 1024 + jg * 512
                                                   + quad * 128 + l16 * 8];
                lacc = mfma16(pf, ones, lacc);
                #pragma unroll
                for (int dg = 0; dg < 4; dg++) {
                    bf16x8 vf = *(const bf16x8*)&vl[(dg * 16 + l16) * 64
                                                    + (((jg * 4 + quad) ^ sw) * 8)];
                    acc[dg] = mfma16(pf, vf, acc[dg]);
                }
            }
            __builtin_amdgcn_s_setprio(0);
        }

        float linv[4];
        #pragma unroll
        for (int r = 0; r < 4; r++)
            linv[r] = 1.0f / lacc[r];
        #pragma unroll
        for (int dg = 0; dg < 4; dg++)
            #pragma unroll
            for (int r = 0; r < 4; r++) {
                const float o = acc[dg][r] * linv[r];
                const int i = i0 + w * 16 + quad * 4 + r;
                attn_ws[(((size_t)(b * NSEQ + i)) * HEADS + h) * DHEAD + dg * 16 + l16] =
                    f2bf(o);
            }
    }
}

// =====================================================================
// Kernel 3 v6 (unchanged, passed r7/r9/r11): dbuf + counted-vmcnt.
// =====================================================================
__global__ __launch_bounds__(256) void out_gemm_v6(
    const u16* __restrict__ attn, const u16* __restrict__ Wot,
    const float* __restrict__ bo, float* __restrict__ out)
{
    __shared__ u16 As[2][2][128 * 32];
    __shared__ u16 Bs[2][2][128 * 32];

    const int n0 = blockIdx.x * 128;
    const int m0 = blockIdx.y * 128;
    const int t = threadIdx.x, lane = t & 63, w = t >> 6;
    const int wr = w >> 1, wc = w & 1;
    const int quad = lane >> 4, l16 = lane & 15;
    const int lrow = lane >> 2;
    const int lk = (((lane & 3) ^ ((lane >> 3) & 3)) * 8);
    const int rsw = ((l16 >> 1) & 3);

    floatx4 acc[4][4];
    #pragma unroll
    for (int i = 0; i < 4; i++)
        #pragma unroll
        for (int j = 0; j < 4; j++) acc[i][j] = floatx4{0.f, 0.f, 0.f, 0.f};

#define STAGE_O6(kt, buf) do {                                             \
    const size_t k0s = (size_t)(kt) * 64;                                  \
    _Pragma("unroll")                                                      \
    for (int hh = 0; hh < 2; hh++) {                                       \
        const int row = w * 32 + hh * 16;                                  \
        const size_t ga = (size_t)(m0 + row + lrow) * DIM + k0s + lk;      \
        const size_t gb = (size_t)(n0 + row + lrow) * DIM + k0s + lk;      \
        gld16(&attn[ga],      &As[buf][0][row * 32]);                      \
        gld16(&attn[ga + 32], &As[buf][1][row * 32]);                      \
        gld16(&Wot[gb],       &Bs[buf][0][row * 32]);                      \
        gld16(&Wot[gb + 32],  &Bs[buf][1][row * 32]);                      \
    }                                                                      \
} while (0)

    STAGE_O6(0, 0);
    STAGE_O6(1, 1);

    for (int kt = 0; kt < 16; kt++) {
        const int cur = kt & 1;
        if (kt < 15) asm volatile("s_waitcnt vmcnt(8)" ::: "memory");
        else         asm volatile("s_waitcnt vmcnt(0)" ::: "memory");
        __builtin_amdgcn_s_barrier();
        __builtin_amdgcn_sched_barrier(0);

        #pragma unroll
        for (int ks = 0; ks < 2; ks++) {
            const u16* al = &As[cur][ks][0];
            const u16* bl = &Bs[cur][ks][0];
            bf16x8 af[4], bf[4];
            #pragma unroll
            for (int i = 0; i < 4; i++)
                af[i] = *(const bf16x8*)&al[(wr * 64 + i * 16 + l16) * 32
                                            + ((quad ^ rsw) * 8)];
            #pragma unroll
            for (int j = 0; j < 4; j++)
                bf[j] = *(const bf16x8*)&bl[(wc * 64 + j * 16 + l16) * 32
                                            + ((quad ^ rsw) * 8)];
            __builtin_amdgcn_s_setprio(1);
            #pragma unroll
            for (int i = 0; i < 4; i++)
                #pragma unroll
                for (int j = 0; j < 4; j++)
                    acc[i][j] = mfma16(af[i], bf[j], acc[i][j]);
            __builtin_amdgcn_s_setprio(0);
        }

        __builtin_amdgcn_sched_barrier(0);
        __builtin_amdgcn_s_barrier();
        __builtin_amdgcn_sched_barrier(0);
        if (kt < 14) STAGE_O6(kt + 2, cur);
    }
#undef STAGE_O6

    #pragma unroll
    for (int j = 0; j < 4; j++) {
        const int n = n0 + wc * 64 + j * 16 + l16;
        const float bias = bo[n];
        #pragma unroll
        for (int i = 0; i < 4; i++) {
            #pragma unroll
            for (int r = 0; r < 4; r++) {
                const int m = m0 + wr * 64 + i * 16 + quad * 4 + r;
                out[(size_t)m * DIM + n] = acc[i][j][r] + bias;
            }
        }
    }
}

// =====================================================================
extern "C" void kernel_launch(void* const* d_in, const int* in_sizes, int n_in,
                              void* d_out, int out_size, void* d_ws, size_t ws_size,
                              hipStream_t stream) {
    const float* x   = (const float*)d_in[0];
    const float* Wq  = (const float*)d_in[1];
    const float* Wkv = (const float*)d_in[2];
    const float* Wo  = (const float*)d_in[3];
    const float* bo  = (const float*)d_in[4];

    u16* q_ws = (u16*)d_out;
    u16* xb   = (u16*)d_out + (size_t)8388608;

    u16* ws   = (u16*)d_ws;
    u16* k_ws = ws;                          // [0,16M)   K bf16; later Wot
    u16* v_ws = ws + (size_t)8388608;        // [16M,32M) V bf16
    u16* a_ws = ws + (size_t)16777216;       // [32M,48M) Wt then attn out
    u16* Wt   = a_ws;
    u16* Wot  = k_ws;

    prep_fused<<<4864, 256, 0, stream>>>(x, xb, Wq, Wkv, Wt);
    qkv_gemm_v7<<<dim3(24, 32), 512, 0, stream>>>(xb, Wt, q_ws, k_ws, v_ws);
    attn_v11<<<dim3(1024), 256, 0, stream>>>(q_ws, k_ws, v_ws, a_ws);
    transpose_conv<<<dim3(16, 16), 256, 0, stream>>>(Wo, Wot, 1024);
    out_gemm_v6<<<dim3(8, 64), 256, 0, stream>>>(a_ws, Wot, bo, (float*)d_out);
}

// Round 13
// 246.221 us; speedup vs baseline: 1.0177x; 1.0177x over previous
//
#include <hip/hip_runtime.h>

typedef unsigned short u16;
typedef __bf16 bf16x8 __attribute__((ext_vector_type(8)));
typedef float floatx4 __attribute__((ext_vector_type(4)));
typedef unsigned as1_u32 __attribute__((address_space(1)));
typedef unsigned as3_u32 __attribute__((address_space(3)));

// ---- helpers ----
__device__ inline u16 f2bf(float f) {
    unsigned int u = __builtin_bit_cast(unsigned int, f);
    u += 0x7fffu + ((u >> 16) & 1u);   // RNE
    return (u16)(u >> 16);
}
__device__ inline floatx4 mfma16(bf16x8 a, bf16x8 b, floatx4 c) {
    return __builtin_amdgcn_mfma_f32_16x16x32_bf16(a, b, c, 0, 0, 0);
}
// async global->LDS, 16 B per lane; lds base must be wave-uniform (HW adds lane*16)
__device__ inline void gld16(const u16* g, u16* l) {
    __builtin_amdgcn_global_load_lds((const as1_u32*)g, (as3_u32*)l, 16, 0, 0);
}
// hi16(a) | hi16(b)<<16 via v_perm_b32  (bf16 truncation pack)
__device__ inline unsigned permpack(float lo, float hi) {
    return __builtin_amdgcn_perm(__builtin_bit_cast(unsigned, hi),
                                 __builtin_bit_cast(unsigned, lo), 0x07060302u);
}

#define NSEQ 2048
#define DIM  1024
#define HEADS 16
#define DHEAD 64
// Q pre-scale folds softmax scale AND log2(e): 0.125 * 1.44269504
#define QSCALE 0.18033688f
// fixed softmax shift (log2 domain)
#define CSHIFT 4.328085f

// =====================================================================
// Fused pre-pass: block-range dispatch.
// =====================================================================
__device__ inline void transpose_tile(const float* __restrict__ src,
                                      u16* __restrict__ dst, int ncols,
                                      int n0, int k0, int t) {
    __shared__ u16 tile[64][72];
    #pragma unroll
    for (int rr = 0; rr < 4; rr++) {
        const int k = (t >> 4) + rr * 16;
        const int n = (t & 15) * 4;
        float4 v = *(const float4*)&src[(size_t)(k0 + k) * ncols + n0 + n];
        tile[n + 0][k] = f2bf(v.x); tile[n + 1][k] = f2bf(v.y);
        tile[n + 2][k] = f2bf(v.z); tile[n + 3][k] = f2bf(v.w);
    }
    __syncthreads();
    #pragma unroll
    for (int ww = 0; ww < 2; ww++) {
        const int idx = t + ww * 256;
        const int n = idx >> 3, g = idx & 7;
        u16 tmp[8] __attribute__((aligned(16)));
        #pragma unroll
        for (int i = 0; i < 8; i++) tmp[i] = tile[n][g * 8 + i];
        *(uint4*)&dst[(size_t)(n0 + n) * 1024 + k0 + g * 8] = *(const uint4*)tmp;
    }
}

__global__ __launch_bounds__(256) void prep_fused(
    const float* __restrict__ x,  u16* __restrict__ xb,
    const float* __restrict__ Wq, const float* __restrict__ Wkv,
    u16* __restrict__ Wt)
{
    const int bid = blockIdx.x;
    const int t = threadIdx.x;
    if (bid < 4096) {
        const size_t i = ((size_t)bid * 256 + t) * 8;
        float4 a = *(const float4*)&x[i];
        float4 b = *(const float4*)&x[i + 4];
        u16 o[8] __attribute__((aligned(16)));
        o[0] = f2bf(a.x); o[1] = f2bf(a.y); o[2] = f2bf(a.z); o[3] = f2bf(a.w);
        o[4] = f2bf(b.x); o[5] = f2bf(b.y); o[6] = f2bf(b.z); o[7] = f2bf(b.w);
        *(uint4*)&xb[i] = *(const uint4*)o;
    } else if (bid < 4352) {
        const int v = bid - 4096;
        transpose_tile(Wq, Wt, 1024, (v & 15) * 64, (v >> 4) * 64, t);
    } else {
        const int v = bid - 4352;
        transpose_tile(Wkv, Wt + (size_t)1024 * 1024, 2048, (v & 31) * 64, (v >> 5) * 64, t);
    }
}

__global__ __launch_bounds__(256) void transpose_conv(const float* __restrict__ src,
                                                      u16* __restrict__ dst, int ncols) {
    transpose_tile(src, dst, ncols, blockIdx.x * 64, blockIdx.y * 64, threadIdx.x);
}

// =====================================================================
// Kernel 1 v8: v6's verified skeleton (dbuf + counted vmcnt + raw
// barrier pairs + zero-conflict swizzle) with BK 64->32:
//   32KB LDS -> 4 blocks/CU (16 waves/CU, 2x v6's TLP), 4 gld/wave/tile,
//   vmcnt(4) counted wait, 32 K-iterations.
// =====================================================================
__global__ __launch_bounds__(256) void qkv_gemm_v8(
    const u16* __restrict__ xb, const u16* __restrict__ Wt,
    u16* __restrict__ q_ws, u16* __restrict__ k_ws, u16* __restrict__ v_ws)
{
    __shared__ u16 As[2][128 * 32];   // [buf][128 rows x 32 cols]
    __shared__ u16 Bs[2][128 * 32];

    const int n0 = blockIdx.x * 128;
    const int m0 = blockIdx.y * 128;
    const int t = threadIdx.x, lane = t & 63, w = t >> 6;
    const int wr = w >> 1, wc = w & 1;
    const int quad = lane >> 4, l16 = lane & 15;
    const int lrow = lane >> 2;
    // pre-swizzled source chunk (zero-conflict, verified r5): c ^ ((row>>1)&3)
    const int lk = (((lane & 3) ^ ((lane >> 3) & 3)) * 8);
    const int rsw = ((l16 >> 1) & 3);            // read-side swizzle key

    floatx4 acc[4][4];
    #pragma unroll
    for (int i = 0; i < 4; i++)
        #pragma unroll
        for (int j = 0; j < 4; j++) acc[i][j] = floatx4{0.f, 0.f, 0.f, 0.f};

#define STAGE_V8(kt, buf) do {                                             \
    const size_t k0s = (size_t)(kt) * 32;                                  \
    _Pragma("unroll")                                                      \
    for (int hh = 0; hh < 2; hh++) {                                       \
        const int row = w * 32 + hh * 16;                                  \
        const size_t ga = (size_t)(m0 + row + lrow) * DIM + k0s + lk;      \
        const size_t gb = (size_t)(n0 + row + lrow) * DIM + k0s + lk;      \
        gld16(&xb[ga], &As[buf][row * 32]);                                \
        gld16(&Wt[gb], &Bs[buf][row * 32]);                                \
    }                                                                      \
} while (0)

    // prologue: K-tiles 0,1 -> bufs 0,1  (8 issues/wave outstanding)
    STAGE_V8(0, 0);
    STAGE_V8(1, 1);

    for (int kt = 0; kt < 32; kt++) {
        const int cur = kt & 1;
        // wait only the oldest 4 (current tile); keep next tile in flight
        if (kt < 31) asm volatile("s_waitcnt vmcnt(4)" ::: "memory");
        else         asm volatile("s_waitcnt vmcnt(0)" ::: "memory");
        __builtin_amdgcn_s_barrier();            // publish buf[cur]
        __builtin_amdgcn_sched_barrier(0);       // no ds_read above this point

        {
            const u16* al = &As[cur][0];
            const u16* bl = &Bs[cur][0];
            bf16x8 af[4], bf[4];
            #pragma unroll
            for (int i = 0; i < 4; i++)
                af[i] = *(const bf16x8*)&al[(wr * 64 + i * 16 + l16) * 32
                                            + ((quad ^ rsw) * 8)];
            #pragma unroll
            for (int j = 0; j < 4; j++)
                bf[j] = *(const bf16x8*)&bl[(wc * 64 + j * 16 + l16) * 32
                                            + ((quad ^ rsw) * 8)];
            __builtin_amdgcn_s_setprio(1);
            #pragma unroll
            for (int i = 0; i < 4; i++)
                #pragma unroll
                for (int j = 0; j < 4; j++)
                    acc[i][j] = mfma16(af[i], bf[j], acc[i][j]);
            __builtin_amdgcn_s_setprio(0);
        }

        __builtin_amdgcn_sched_barrier(0);       // reads finished above
        __builtin_amdgcn_s_barrier();            // release buf[cur]
        __builtin_amdgcn_sched_barrier(0);       // no stage above release
        if (kt < 30) STAGE_V8(kt + 2, cur);
    }
#undef STAGE_V8

    const int seg = n0 >> 10;
    #pragma unroll
    for (int j = 0; j < 4; j++) {
        const int n  = n0 + wc * 64 + j * 16 + l16;
        const int nn = n & 1023;
        const int h  = nn >> 6, d = nn & 63;
        #pragma unroll
        for (int i = 0; i < 4; i++) {
            const int mb = m0 + wr * 64 + i * 16 + quad * 4;
            const int b = mb >> 11, ib = mb & (NSEQ - 1);
            if (seg == 0) {
                #pragma unroll
                for (int r = 0; r < 4; r++)
                    q_ws[(((size_t)(b * HEADS + h)) * NSEQ + ib + r) * DHEAD + d] =
                        f2bf(acc[i][j][r] * QSCALE);
            } else if (seg == 1) {
                #pragma unroll
                for (int r = 0; r < 4; r++)
                    k_ws[(((size_t)(b * HEADS + h)) * NSEQ + ib + r) * DHEAD + d] =
                        f2bf(acc[i][j][r]);
            } else {
                u16 tmp[4] __attribute__((aligned(8)));
                #pragma unroll
                for (int r = 0; r < 4; r++) tmp[r] = f2bf(acc[i][j][r]);
                *(uint2*)&v_ws[(((size_t)(b * HEADS + h)) * DHEAD + d) * NSEQ + ib] =
                    *(const uint2*)tmp;
            }
        }
    }
}

// =====================================================================
// Kernel 2 v11 (unchanged, passed r11): balanced pairing + ones-MFMA l.
// =====================================================================
__global__ __launch_bounds__(256) void attn_v11(
    const u16* __restrict__ q_ws, const u16* __restrict__ k_ws,
    const u16* __restrict__ v_ws, u16* __restrict__ attn_ws)
{
    __shared__ u16 kds[2][64 * 64];       // [j][chunk-swizzled d]
    __shared__ u16 vds[2][64 * 64];       // [d][chunk-swizzled j]
    __shared__ u16 p_lds[4 * 1024];       // per-wave 2KB, chunk-column-major

    const int bid = blockIdx.x;           // 1024 = 16 pairs x 64 bh
    const int bh  = bid & 63;
    const int pr  = bid >> 6;             // 0..15
    const int b   = bh >> 4, h = bh & 15;

    const u16* qb = q_ws + (size_t)bh * NSEQ * DHEAD;
    const u16* kb = k_ws + (size_t)bh * NSEQ * DHEAD;
    const u16* vb = v_ws + (size_t)bh * DHEAD * NSEQ;

    const int t    = threadIdx.x;
    const int lane = t & 63, w = t >> 6;
    const int quad = lane >> 4, l16 = lane & 15;

    const int srow8 = lane >> 3;
    const int chunk = (lane & 7) ^ srow8;
    const int krow  = w * 16 + srow8;
    const size_t koff = (size_t)krow * DHEAD + chunk * 8;
    const size_t voff = (size_t)krow * NSEQ + chunk * 8;
    u16* klbase = (u16*)&kds[0][0] + w * 1024;
    u16* vlbase = (u16*)&vds[0][0] + w * 1024;
    const int sw = (l16 & 7);

    bf16x8 ones;
    #pragma unroll
    for (int i = 0; i < 8; i++) ones[i] = (__bf16)1.0f;

    for (int seg = 0; seg < 2; seg++) {
        const int tq = seg ? pr : (31 - pr);     // heavy tile first
        const int i0 = tq * 64;
        const int jt_max = tq;

        bf16x8 qf[2];
        #pragma unroll
        for (int dg = 0; dg < 2; dg++)
            qf[dg] = *(const bf16x8*)&qb[(size_t)(i0 + w * 16 + l16) * DHEAD
                                         + dg * 32 + quad * 8];

        floatx4 lacc = floatx4{0.f, 0.f, 0.f, 0.f};
        floatx4 acc[4];
        #pragma unroll
        for (int dg = 0; dg < 4; dg++) acc[dg] = floatx4{0.f, 0.f, 0.f, 0.f};

        __syncthreads();   // protect K/V buffers vs previous segment's reads
        gld16(&kb[koff],             klbase);
        gld16(&kb[koff + 8 * DHEAD], klbase + 512);
        gld16(&vb[voff],             vlbase);
        gld16(&vb[voff + 8 * NSEQ],  vlbase + 512);

        for (int jt = 0; jt <= jt_max; jt++) {
            const int cur = jt & 1;
            __syncthreads();   // drains vmcnt+lgkmcnt: buf[cur] ready

            if (jt < jt_max) {
                const size_t j64 = (size_t)(jt + 1) * 64;
                const int nb = (cur ^ 1) * 4096;
                gld16(&kb[j64 * DHEAD + koff],             klbase + nb);
                gld16(&kb[j64 * DHEAD + koff + 8 * DHEAD], klbase + nb + 512);
                gld16(&vb[j64 + voff],                     vlbase + nb);
                gld16(&vb[j64 + voff + 8 * NSEQ],          vlbase + nb + 512);
            }

            const u16* kl = &kds[cur][0];
            const u16* vl = &vds[cur][0];
            const int j0 = jt * 64;

            floatx4 s[4];
            #pragma unroll
            for (int g = 0; g < 4; g++)
                s[g] = floatx4{-CSHIFT, -CSHIFT, -CSHIFT, -CSHIFT};
            __builtin_amdgcn_s_setprio(1);
            #pragma unroll
            for (int dg = 0; dg < 2; dg++)
                #pragma unroll
                for (int g = 0; g < 4; g++) {
                    bf16x8 kf = *(const bf16x8*)&kl[(g * 16 + l16) * 64
                                                    + (((dg * 4 + quad) ^ sw) * 8)];
                    s[g] = mfma16(kf, qf[dg], s[g]);
                }
            __builtin_amdgcn_s_setprio(0);

            if (j0 + 63 > i0 + w * 16) {
                const int i = i0 + w * 16 + l16;
                #pragma unroll
                for (int g = 0; g < 4; g++) {
                    const int jb = j0 + g * 16 + quad * 4;
                    #pragma unroll
                    for (int r = 0; r < 4; r++)
                        if (jb + r > i) s[g][r] = -1e30f;
                }
            }

            #pragma unroll
            for (int g = 0; g < 4; g++) {
                #pragma unroll
                for (int r = 0; r < 4; r++)
                    s[g][r] = __builtin_amdgcn_exp2f(s[g][r]);
                uint2 pk;
                pk.x = permpack(s[g][0], s[g][1]);
                pk.y = permpack(s[g][2], s[g][3]);
                const int c = 2 * g + (quad >> 1);
                *(uint2*)&p_lds[w * 1024 + (c >> 2) * 512 + (c & 3) * 128
                                + l16 * 8 + (quad & 1) * 4] = pk;
            }
            asm volatile("s_waitcnt lgkmcnt(0)" ::: "memory");

            __builtin_amdgcn_s_setprio(1);
            #pragma unroll
            for (int jg = 0; jg < 2; jg++) {
                bf16x8 pf = *(const bf16x8*)&p_lds[w * 1024 + jg * 512
                                                   + quad * 128 + l16 * 8];
                lacc = mfma16(pf, ones, lacc);
                #pragma unroll
                for (int dg = 0; dg < 4; dg++) {
                    bf16x8 vf = *(const bf16x8*)&vl[(dg * 16 + l16) * 64
                                                    + (((jg * 4 + quad) ^ sw) * 8)];
                    acc[dg] = mfma16(pf, vf, acc[dg]);
                }
            }
            __builtin_amdgcn_s_setprio(0);
        }

        float linv[4];
        #pragma unroll
        for (int r = 0; r < 4; r++)
            linv[r] = 1.0f / lacc[r];
        #pragma unroll
        for (int dg = 0; dg < 4; dg++)
            #pragma unroll
            for (int r = 0; r < 4; r++) {
                const float o = acc[dg][r] * linv[r];
                const int i = i0 + w * 16 + quad * 4 + r;
                attn_ws[(((size_t)(b * NSEQ + i)) * HEADS + h) * DHEAD + dg * 16 + l16] =
                    f2bf(o);
            }
    }
}

// =====================================================================
// Kernel 3 v6 (unchanged, passed r7/r9/r11): dbuf + counted-vmcnt.
// =====================================================================
__global__ __launch_bounds__(256) void out_gemm_v6(
    const u16* __restrict__ attn, const u16* __restrict__ Wot,
    const float* __restrict__ bo, float* __restrict__ out)
{
    __shared__ u16 As[2][2][128 * 32];
    __shared__ u16 Bs[2][2][128 * 32];

    const int n0 = blockIdx.x * 128;
    const int m0 = blockIdx.y * 128;
    const int t = threadIdx.x, lane = t & 63, w = t >> 6;
    const int wr = w >> 1, wc = w & 1;
    const int quad = lane >> 4, l16 = lane & 15;
    const int lrow = lane >> 2;
    const int lk = (((lane & 3) ^ ((lane >> 3) & 3)) * 8);
    const int rsw = ((l16 >> 1) & 3);

    floatx4 acc[4][4];
    #pragma unroll
    for (int i = 0; i < 4; i++)
        #pragma unroll
        for (int j = 0; j < 4; j++) acc[i][j] = floatx4{0.f, 0.f, 0.f, 0.f};

#define STAGE_O6(kt, buf) do {                                             \
    const size_t k0s = (size_t)(kt) * 64;                                  \
    _Pragma("unroll")                                                      \
    for (int hh = 0; hh < 2; hh++) {                                       \
        const int row = w * 32 + hh * 16;                                  \
        const size_t ga = (size_t)(m0 + row + lrow) * DIM + k0s + lk;      \
        const size_t gb = (size_t)(n0 + row + lrow) * DIM + k0s + lk;      \
        gld16(&attn[ga],      &As[buf][0][row * 32]);                      \
        gld16(&attn[ga + 32], &As[buf][1][row * 32]);                      \
        gld16(&Wot[gb],       &Bs[buf][0][row * 32]);                      \
        gld16(&Wot[gb + 32],  &Bs[buf][1][row * 32]);                      \
    }                                                                      \
} while (0)

    STAGE_O6(0, 0);
    STAGE_O6(1, 1);

    for (int kt = 0; kt < 16; kt++) {
        const int cur = kt & 1;
        if (kt < 15) asm volatile("s_waitcnt vmcnt(8)" ::: "memory");
        else         asm volatile("s_waitcnt vmcnt(0)" ::: "memory");
        __builtin_amdgcn_s_barrier();
        __builtin_amdgcn_sched_barrier(0);

        #pragma unroll
        for (int ks = 0; ks < 2; ks++) {
            const u16* al = &As[cur][ks][0];
            const u16* bl = &Bs[cur][ks][0];
            bf16x8 af[4], bf[4];
            #pragma unroll
            for (int i = 0; i < 4; i++)
                af[i] = *(const bf16x8*)&al[(wr * 64 + i * 16 + l16) * 32
                                            + ((quad ^ rsw) * 8)];
            #pragma unroll
            for (int j = 0; j < 4; j++)
                bf[j] = *(const bf16x8*)&bl[(wc * 64 + j * 16 + l16) * 32
                                            + ((quad ^ rsw) * 8)];
            __builtin_amdgcn_s_setprio(1);
            #pragma unroll
            for (int i = 0; i < 4; i++)
                #pragma unroll
                for (int j = 0; j < 4; j++)
                    acc[i][j] = mfma16(af[i], bf[j], acc[i][j]);
            __builtin_amdgcn_s_setprio(0);
        }

        __builtin_amdgcn_sched_barrier(0);
        __builtin_amdgcn_s_barrier();
        __builtin_amdgcn_sched_barrier(0);
        if (kt < 14) STAGE_O6(kt + 2, cur);
    }
#undef STAGE_O6

    #pragma unroll
    for (int j = 0; j < 4; j++) {
        const int n = n0 + wc * 64 + j * 16 + l16;
        const float bias = bo[n];
        #pragma unroll
        for (int i = 0; i < 4; i++) {
            #pragma unroll
            for (int r = 0; r < 4; r++) {
                const int m = m0 + wr * 64 + i * 16 + quad * 4 + r;
                out[(size_t)m * DIM + n] = acc[i][j][r] + bias;
            }
        }
    }
}

// =====================================================================
extern "C" void kernel_launch(void* const* d_in, const int* in_sizes, int n_in,
                              void* d_out, int out_size, void* d_ws, size_t ws_size,
                              hipStream_t stream) {
    const float* x   = (const float*)d_in[0];
    const float* Wq  = (const float*)d_in[1];
    const float* Wkv = (const float*)d_in[2];
    const float* Wo  = (const float*)d_in[3];
    const float* bo  = (const float*)d_in[4];

    u16* q_ws = (u16*)d_out;
    u16* xb   = (u16*)d_out + (size_t)8388608;

    u16* ws   = (u16*)d_ws;
    u16* k_ws = ws;                          // [0,16M)   K bf16; later Wot
    u16* v_ws = ws + (size_t)8388608;        // [16M,32M) V bf16
    u16* a_ws = ws + (size_t)16777216;       // [32M,48M) Wt then attn out
    u16* Wt   = a_ws;
    u16* Wot  = k_ws;

    prep_fused<<<4864, 256, 0, stream>>>(x, xb, Wq, Wkv, Wt);
    qkv_gemm_v8<<<dim3(24, 64), 256, 0, stream>>>(xb, Wt, q_ws, k_ws, v_ws);
    attn_v11<<<dim3(1024), 256, 0, stream>>>(q_ws, k_ws, v_ws, a_ws);
    transpose_conv<<<dim3(16, 16), 256, 0, stream>>>(Wo, Wot, 1024);
    out_gemm_v6<<<dim3(8, 64), 256, 0, stream>>>(a_ws, Wot, bo, (float*)d_out);
}

// Round 14
// 242.826 us; speedup vs baseline: 1.0320x; 1.0140x over previous
//
#include <hip/hip_runtime.h>

typedef unsigned short u16;
typedef __bf16 bf16x8 __attribute__((ext_vector_type(8)));
typedef float floatx4 __attribute__((ext_vector_type(4)));
typedef unsigned as1_u32 __attribute__((address_space(1)));
typedef unsigned as3_u32 __attribute__((address_space(3)));

// ---- helpers ----
__device__ inline u16 f2bf(float f) {
    unsigned int u = __builtin_bit_cast(unsigned int, f);
    u += 0x7fffu + ((u >> 16) & 1u);   // RNE
    return (u16)(u >> 16);
}
__device__ inline floatx4 mfma16(bf16x8 a, bf16x8 b, floatx4 c) {
    return __builtin_amdgcn_mfma_f32_16x16x32_bf16(a, b, c, 0, 0, 0);
}
// async global->LDS, 16 B per lane; lds base must be wave-uniform (HW adds lane*16)
__device__ inline void gld16(const u16* g, u16* l) {
    __builtin_amdgcn_global_load_lds((const as1_u32*)g, (as3_u32*)l, 16, 0, 0);
}
// hi16(a) | hi16(b)<<16 via v_perm_b32  (bf16 truncation pack)
__device__ inline unsigned permpack(float lo, float hi) {
    return __builtin_amdgcn_perm(__builtin_bit_cast(unsigned, hi),
                                 __builtin_bit_cast(unsigned, lo), 0x07060302u);
}

#define NSEQ 2048
#define DIM  1024
#define HEADS 16
#define DHEAD 64
// Q pre-scale folds softmax scale AND log2(e): 0.125 * 1.44269504
#define QSCALE 0.18033688f
// fixed softmax shift (log2 domain)
#define CSHIFT 4.328085f

// =====================================================================
// Fused pre-pass: block-range dispatch.
//   [0, 4096)      : x fp32 -> bf16 copy-convert
//   [4096, 4352)   : Wq  transpose-convert
//   [4352, 4864)   : Wkv transpose-convert
//   [4864, 5120)   : Wo  transpose-convert (only when ws has room; grid
//                    is launched with 4864 blocks otherwise)
// =====================================================================
__device__ inline void transpose_tile(const float* __restrict__ src,
                                      u16* __restrict__ dst, int ncols,
                                      int n0, int k0, int t) {
    __shared__ u16 tile[64][72];
    #pragma unroll
    for (int rr = 0; rr < 4; rr++) {
        const int k = (t >> 4) + rr * 16;
        const int n = (t & 15) * 4;
        float4 v = *(const float4*)&src[(size_t)(k0 + k) * ncols + n0 + n];
        tile[n + 0][k] = f2bf(v.x); tile[n + 1][k] = f2bf(v.y);
        tile[n + 2][k] = f2bf(v.z); tile[n + 3][k] = f2bf(v.w);
    }
    __syncthreads();
    #pragma unroll
    for (int ww = 0; ww < 2; ww++) {
        const int idx = t + ww * 256;
        const int n = idx >> 3, g = idx & 7;
        u16 tmp[8] __attribute__((aligned(16)));
        #pragma unroll
        for (int i = 0; i < 8; i++) tmp[i] = tile[n][g * 8 + i];
        *(uint4*)&dst[(size_t)(n0 + n) * 1024 + k0 + g * 8] = *(const uint4*)tmp;
    }
}

__global__ __launch_bounds__(256) void prep_fused(
    const float* __restrict__ x,  u16* __restrict__ xb,
    const float* __restrict__ Wq, const float* __restrict__ Wkv,
    u16* __restrict__ Wt,
    const float* __restrict__ Wo, u16* __restrict__ WotF)
{
    const int bid = blockIdx.x;
    const int t = threadIdx.x;
    if (bid < 4096) {
        const size_t i = ((size_t)bid * 256 + t) * 8;
        float4 a = *(const float4*)&x[i];
        float4 b = *(const float4*)&x[i + 4];
        u16 o[8] __attribute__((aligned(16)));
        o[0] = f2bf(a.x); o[1] = f2bf(a.y); o[2] = f2bf(a.z); o[3] = f2bf(a.w);
        o[4] = f2bf(b.x); o[5] = f2bf(b.y); o[6] = f2bf(b.z); o[7] = f2bf(b.w);
        *(uint4*)&xb[i] = *(const uint4*)o;
    } else if (bid < 4352) {
        const int v = bid - 4096;
        transpose_tile(Wq, Wt, 1024, (v & 15) * 64, (v >> 4) * 64, t);
    } else if (bid < 4864) {
        const int v = bid - 4352;
        transpose_tile(Wkv, Wt + (size_t)1024 * 1024, 2048, (v & 31) * 64, (v >> 5) * 64, t);
    } else {
        const int v = bid - 4864;
        transpose_tile(Wo, WotF, 1024, (v & 15) * 64, (v >> 4) * 64, t);
    }
}

__global__ __launch_bounds__(256) void transpose_conv(const float* __restrict__ src,
                                                      u16* __restrict__ dst, int ncols) {
    transpose_tile(src, dst, ncols, blockIdx.x * 64, blockIdx.y * 64, threadIdx.x);
}

// =====================================================================
// Kernel 1 v6 (verified best, r7/r9/r11): dbuf + counted vmcnt + swizzle.
// =====================================================================
__global__ __launch_bounds__(256) void qkv_gemm_v6(
    const u16* __restrict__ xb, const u16* __restrict__ Wt,
    u16* __restrict__ q_ws, u16* __restrict__ k_ws, u16* __restrict__ v_ws)
{
    __shared__ u16 As[2][2][128 * 32];   // [buf][ks(32-col half)]
    __shared__ u16 Bs[2][2][128 * 32];

    const int n0 = blockIdx.x * 128;
    const int m0 = blockIdx.y * 128;
    const int t = threadIdx.x, lane = t & 63, w = t >> 6;
    const int wr = w >> 1, wc = w & 1;
    const int quad = lane >> 4, l16 = lane & 15;
    const int lrow = lane >> 2;
    const int lk = (((lane & 3) ^ ((lane >> 3) & 3)) * 8);
    const int rsw = ((l16 >> 1) & 3);            // read-side swizzle key

    floatx4 acc[4][4];
    #pragma unroll
    for (int i = 0; i < 4; i++)
        #pragma unroll
        for (int j = 0; j < 4; j++) acc[i][j] = floatx4{0.f, 0.f, 0.f, 0.f};

#define STAGE_V6(kt, buf) do {                                             \
    const size_t k0s = (size_t)(kt) * 64;                                  \
    _Pragma("unroll")                                                      \
    for (int hh = 0; hh < 2; hh++) {                                       \
        const int row = w * 32 + hh * 16;                                  \
        const size_t ga = (size_t)(m0 + row + lrow) * DIM + k0s + lk;      \
        const size_t gb = (size_t)(n0 + row + lrow) * DIM + k0s + lk;      \
        gld16(&xb[ga],      &As[buf][0][row * 32]);                        \
        gld16(&xb[ga + 32], &As[buf][1][row * 32]);                        \
        gld16(&Wt[gb],      &Bs[buf][0][row * 32]);                        \
        gld16(&Wt[gb + 32], &Bs[buf][1][row * 32]);                        \
    }                                                                      \
} while (0)

    STAGE_V6(0, 0);
    STAGE_V6(1, 1);

    for (int kt = 0; kt < 16; kt++) {
        const int cur = kt & 1;
        if (kt < 15) asm volatile("s_waitcnt vmcnt(8)" ::: "memory");
        else         asm volatile("s_waitcnt vmcnt(0)" ::: "memory");
        __builtin_amdgcn_s_barrier();            // publish buf[cur]
        __builtin_amdgcn_sched_barrier(0);

        #pragma unroll
        for (int ks = 0; ks < 2; ks++) {
            const u16* al = &As[cur][ks][0];
            const u16* bl = &Bs[cur][ks][0];
            bf16x8 af[4], bf[4];
            #pragma unroll
            for (int i = 0; i < 4; i++)
                af[i] = *(const bf16x8*)&al[(wr * 64 + i * 16 + l16) * 32
                                            + ((quad ^ rsw) * 8)];
            #pragma unroll
            for (int j = 0; j < 4; j++)
                bf[j] = *(const bf16x8*)&bl[(wc * 64 + j * 16 + l16) * 32
                                            + ((quad ^ rsw) * 8)];
            __builtin_amdgcn_s_setprio(1);
            #pragma unroll
            for (int i = 0; i < 4; i++)
                #pragma unroll
                for (int j = 0; j < 4; j++)
                    acc[i][j] = mfma16(af[i], bf[j], acc[i][j]);
            __builtin_amdgcn_s_setprio(0);
        }

        __builtin_amdgcn_sched_barrier(0);
        __builtin_amdgcn_s_barrier();            // release buf[cur]
        __builtin_amdgcn_sched_barrier(0);
        if (kt < 14) STAGE_V6(kt + 2, cur);
    }
#undef STAGE_V6

    const int seg = n0 >> 10;
    #pragma unroll
    for (int j = 0; j < 4; j++) {
        const int n  = n0 + wc * 64 + j * 16 + l16;
        const int nn = n & 1023;
        const int h  = nn >> 6, d = nn & 63;
        #pragma unroll
        for (int i = 0; i < 4; i++) {
            const int mb = m0 + wr * 64 + i * 16 + quad * 4;
            const int b = mb >> 11, ib = mb & (NSEQ - 1);
            if (seg == 0) {
                #pragma unroll
                for (int r = 0; r < 4; r++)
                    q_ws[(((size_t)(b * HEADS + h)) * NSEQ + ib + r) * DHEAD + d] =
                        f2bf(acc[i][j][r] * QSCALE);
            } else if (seg == 1) {
                #pragma unroll
                for (int r = 0; r < 4; r++)
                    k_ws[(((size_t)(b * HEADS + h)) * NSEQ + ib + r) * DHEAD + d] =
                        f2bf(acc[i][j][r]);
            } else {
                u16 tmp[4] __attribute__((aligned(8)));
                #pragma unroll
                for (int r = 0; r < 4; r++) tmp[r] = f2bf(acc[i][j][r]);
                *(uint2*)&v_ws[(((size_t)(b * HEADS + h)) * DHEAD + d) * NSEQ + ib] =
                    *(const uint2*)tmp;
            }
        }
    }
}

// =====================================================================
// Kernel 2 v11 (verified, r11): balanced pairing + ones-MFMA row-sum.
// =====================================================================
__global__ __launch_bounds__(256) void attn_v11(
    const u16* __restrict__ q_ws, const u16* __restrict__ k_ws,
    const u16* __restrict__ v_ws, u16* __restrict__ attn_ws)
{
    __shared__ u16 kds[2][64 * 64];       // [j][chunk-swizzled d]
    __shared__ u16 vds[2][64 * 64];       // [d][chunk-swizzled j]
    __shared__ u16 p_lds[4 * 1024];       // per-wave 2KB, chunk-column-major

    const int bid = blockIdx.x;           // 1024 = 16 pairs x 64 bh
    const int bh  = bid & 63;
    const int pr  = bid >> 6;             // 0..15
    const int b   = bh >> 4, h = bh & 15;

    const u16* qb = q_ws + (size_t)bh * NSEQ * DHEAD;
    const u16* kb = k_ws + (size_t)bh * NSEQ * DHEAD;
    const u16* vb = v_ws + (size_t)bh * DHEAD * NSEQ;

    const int t    = threadIdx.x;
    const int lane = t & 63, w = t >> 6;
    const int quad = lane >> 4, l16 = lane & 15;

    const int srow8 = lane >> 3;
    const int chunk = (lane & 7) ^ srow8;
    const int krow  = w * 16 + srow8;
    const size_t koff = (size_t)krow * DHEAD + chunk * 8;
    const size_t voff = (size_t)krow * NSEQ + chunk * 8;
    u16* klbase = (u16*)&kds[0][0] + w * 1024;
    u16* vlbase = (u16*)&vds[0][0] + w * 1024;
    const int sw = (l16 & 7);

    bf16x8 ones;
    #pragma unroll
    for (int i = 0; i < 8; i++) ones[i] = (__bf16)1.0f;

    for (int seg = 0; seg < 2; seg++) {
        const int tq = seg ? pr : (31 - pr);     // heavy tile first
        const int i0 = tq * 64;
        const int jt_max = tq;

        bf16x8 qf[2];
        #pragma unroll
        for (int dg = 0; dg < 2; dg++)
            qf[dg] = *(const bf16x8*)&qb[(size_t)(i0 + w * 16 + l16) * DHEAD
                                         + dg * 32 + quad * 8];

        floatx4 lacc = floatx4{0.f, 0.f, 0.f, 0.f};
        floatx4 acc[4];
        #pragma unroll
        for (int dg = 0; dg < 4; dg++) acc[dg] = floatx4{0.f, 0.f, 0.f, 0.f};

        __syncthreads();   // protect K/V buffers vs previous segment's reads
        gld16(&kb[koff],             klbase);
        gld16(&kb[koff + 8 * DHEAD], klbase + 512);
        gld16(&vb[voff],             vlbase);
        gld16(&vb[voff + 8 * NSEQ],  vlbase + 512);

        for (int jt = 0; jt <= jt_max; jt++) {
            const int cur = jt & 1;
            __syncthreads();   // drains vmcnt+lgkmcnt: buf[cur] ready

            if (jt < jt_max) {
                const size_t j64 = (size_t)(jt + 1) * 64;
                const int nb = (cur ^ 1) * 4096;
                gld16(&kb[j64 * DHEAD + koff],             klbase + nb);
                gld16(&kb[j64 * DHEAD + koff + 8 * DHEAD], klbase + nb + 512);
                gld16(&vb[j64 + voff],                     vlbase + nb);
                gld16(&vb[j64 + voff + 8 * NSEQ],          vlbase + nb + 512);
            }

            const u16* kl = &kds[cur][0];
            const u16* vl = &vds[cur][0];
            const int j0 = jt * 64;

            floatx4 s[4];
            #pragma unroll
            for (int g = 0; g < 4; g++)
                s[g] = floatx4{-CSHIFT, -CSHIFT, -CSHIFT, -CSHIFT};
            __builtin_amdgcn_s_setprio(1);
            #pragma unroll
            for (int dg = 0; dg < 2; dg++)
                #pragma unroll
                for (int g = 0; g < 4; g++) {
                    bf16x8 kf = *(const bf16x8*)&kl[(g * 16 + l16) * 64
                                                    + (((dg * 4 + quad) ^ sw) * 8)];
                    s[g] = mfma16(kf, qf[dg], s[g]);
                }
            __builtin_amdgcn_s_setprio(0);

            if (j0 + 63 > i0 + w * 16) {
                const int i = i0 + w * 16 + l16;
                #pragma unroll
                for (int g = 0; g < 4; g++) {
                    const int jb = j0 + g * 16 + quad * 4;
                    #pragma unroll
                    for (int r = 0; r < 4; r++)
                        if (jb + r > i) s[g][r] = -1e30f;
                }
            }

            #pragma unroll
            for (int g = 0; g < 4; g++) {
                #pragma unroll
                for (int r = 0; r < 4; r++)
                    s[g][r] = __builtin_amdgcn_exp2f(s[g][r]);
                uint2 pk;
                pk.x = permpack(s[g][0], s[g][1]);
                pk.y = permpack(s[g][2], s[g][3]);
                const int c = 2 * g + (quad >> 1);
                *(uint2*)&p_lds[w * 1024 + (c >> 2) * 512 + (c & 3) * 128
                                + l16 * 8 + (quad & 1) * 4] = pk;
            }
            asm volatile("s_waitcnt lgkmcnt(0)" ::: "memory");

            __builtin_amdgcn_s_setprio(1);
            #pragma unroll
            for (int jg = 0; jg < 2; jg++) {
                bf16x8 pf = *(const bf16x8*)&p_lds[w * 1024 + jg * 512
                                                   + quad * 128 + l16 * 8];
                lacc = mfma16(pf, ones, lacc);
                #pragma unroll
                for (int dg = 0; dg < 4; dg++) {
                    bf16x8 vf = *(const bf16x8*)&vl[(dg * 16 + l16) * 64
                                                    + (((jg * 4 + quad) ^ sw) * 8)];
                    acc[dg] = mfma16(pf, vf, acc[dg]);
                }
            }
            __builtin_amdgcn_s_setprio(0);
        }

        float linv[4];
        #pragma unroll
        for (int r = 0; r < 4; r++)
            linv[r] = 1.0f / lacc[r];
        #pragma unroll
        for (int dg = 0; dg < 4; dg++)
            #pragma unroll
            for (int r = 0; r < 4; r++) {
                const float o = acc[dg][r] * linv[r];
                const int i = i0 + w * 16 + quad * 4 + r;
                attn_ws[(((size_t)(b * NSEQ + i)) * HEADS + h) * DHEAD + dg * 16 + l16] =
                    f2bf(o);
            }
    }
}

// =====================================================================
// Kernel 3 v6 (verified, r7/r9/r11): dbuf + counted-vmcnt.
// =====================================================================
__global__ __launch_bounds__(256) void out_gemm_v6(
    const u16* __restrict__ attn, const u16* __restrict__ Wot,
    const float* __restrict__ bo, float* __restrict__ out)
{
    __shared__ u16 As[2][2][128 * 32];
    __shared__ u16 Bs[2][2][128 * 32];

    const int n0 = blockIdx.x * 128;
    const int m0 = blockIdx.y * 128;
    const int t = threadIdx.x, lane = t & 63, w = t >> 6;
    const int wr = w >> 1, wc = w & 1;
    const int quad = lane >> 4, l16 = lane & 15;
    const int lrow = lane >> 2;
    const int lk = (((lane & 3) ^ ((lane >> 3) & 3)) * 8);
    const int rsw = ((l16 >> 1) & 3);

    floatx4 acc[4][4];
    #pragma unroll
    for (int i = 0; i < 4; i++)
        #pragma unroll
        for (int j = 0; j < 4; j++) acc[i][j] = floatx4{0.f, 0.f, 0.f, 0.f};

#define STAGE_O6(kt, buf) do {                                             \
    const size_t k0s = (size_t)(kt) * 64;                                  \
    _Pragma("unroll")                                                      \
    for (int hh = 0; hh < 2; hh++) {                                       \
        const int row = w * 32 + hh * 16;                                  \
        const size_t ga = (size_t)(m0 + row + lrow) * DIM + k0s + lk;      \
        const size_t gb = (size_t)(n0 + row + lrow) * DIM + k0s + lk;      \
        gld16(&attn[ga],      &As[buf][0][row * 32]);                      \
        gld16(&attn[ga + 32], &As[buf][1][row * 32]);                      \
        gld16(&Wot[gb],       &Bs[buf][0][row * 32]);                      \
        gld16(&Wot[gb + 32],  &Bs[buf][1][row * 32]);                      \
    }                                                                      \
} while (0)

    STAGE_O6(0, 0);
    STAGE_O6(1, 1);

    for (int kt = 0; kt < 16; kt++) {
        const int cur = kt & 1;
        if (kt < 15) asm volatile("s_waitcnt vmcnt(8)" ::: "memory");
        else         asm volatile("s_waitcnt vmcnt(0)" ::: "memory");
        __builtin_amdgcn_s_barrier();
        __builtin_amdgcn_sched_barrier(0);

        #pragma unroll
        for (int ks = 0; ks < 2; ks++) {
            const u16* al = &As[cur][ks][0];
            const u16* bl = &Bs[cur][ks][0];
            bf16x8 af[4], bf[4];
            #pragma unroll
            for (int i = 0; i < 4; i++)
                af[i] = *(const bf16x8*)&al[(wr * 64 + i * 16 + l16) * 32
                                            + ((quad ^ rsw) * 8)];
            #pragma unroll
            for (int j = 0; j < 4; j++)
                bf[j] = *(const bf16x8*)&bl[(wc * 64 + j * 16 + l16) * 32
                                            + ((quad ^ rsw) * 8)];
            __builtin_amdgcn_s_setprio(1);
            #pragma unroll
            for (int i = 0; i < 4; i++)
                #pragma unroll
                for (int j = 0; j < 4; j++)
                    acc[i][j] = mfma16(af[i], bf[j], acc[i][j]);
            __builtin_amdgcn_s_setprio(0);
        }

        __builtin_amdgcn_sched_barrier(0);
        __builtin_amdgcn_s_barrier();
        __builtin_amdgcn_sched_barrier(0);
        if (kt < 14) STAGE_O6(kt + 2, cur);
    }
#undef STAGE_O6

    #pragma unroll
    for (int j = 0; j < 4; j++) {
        const int n = n0 + wc * 64 + j * 16 + l16;
        const float bias = bo[n];
        #pragma unroll
        for (int i = 0; i < 4; i++) {
            #pragma unroll
            for (int r = 0; r < 4; r++) {
                const int m = m0 + wr * 64 + i * 16 + quad * 4 + r;
                out[(size_t)m * DIM + n] = acc[i][j][r] + bias;
            }
        }
    }
}

// =====================================================================
extern "C" void kernel_launch(void* const* d_in, const int* in_sizes, int n_in,
                              void* d_out, int out_size, void* d_ws, size_t ws_size,
                              hipStream_t stream) {
    const float* x   = (const float*)d_in[0];
    const float* Wq  = (const float*)d_in[1];
    const float* Wkv = (const float*)d_in[2];
    const float* Wo  = (const float*)d_in[3];
    const float* bo  = (const float*)d_in[4];

    u16* q_ws = (u16*)d_out;
    u16* xb   = (u16*)d_out + (size_t)8388608;

    u16* ws   = (u16*)d_ws;
    u16* k_ws = ws;                          // [0,16M)   K bf16; later Wot (fallback)
    u16* v_ws = ws + (size_t)8388608;        // [16M,32M) V bf16
    u16* a_ws = ws + (size_t)16777216;       // [32M,48M) Wt then attn out
    u16* Wt   = a_ws;

    // Wot placement: fresh region at ws+48MB when workspace allows (fuses
    // the Wo transpose into prep, 5 kernels -> 4); else k_ws after attn.
    const bool fuse_wo = ws_size >= (size_t)50 * 1024 * 1024;
    u16* Wot = fuse_wo ? ws + (size_t)25165824 : k_ws;

    prep_fused<<<fuse_wo ? 5120 : 4864, 256, 0, stream>>>(
        x, xb, Wq, Wkv, Wt, Wo, Wot);
    qkv_gemm_v6<<<dim3(24, 64), 256, 0, stream>>>(xb, Wt, q_ws, k_ws, v_ws);
    attn_v11<<<dim3(1024), 256, 0, stream>>>(q_ws, k_ws, v_ws, a_ws);
    if (!fuse_wo)
        transpose_conv<<<dim3(16, 16), 256, 0, stream>>>(Wo, Wot, 1024);
    out_gemm_v6<<<dim3(8, 64), 256, 0, stream>>>(a_ws, Wot, bo, (float*)d_out);
}